// Round 15
// baseline (195.392 us; speedup 1.0000x reference)
//
#include <hip/hip_runtime.h>
#include <hip/hip_bf16.h>
#include <float.h>

// N=1024, M=1024, D=512, fp32 in/out.
// tanh(q+k) = 1 - 2/(1+exp2(CS*(q+k))), CS=2*log2(e), exp2 factorized:
// eq[n][d]=min(exp2(CS*qp),2^13), ekT[d][m]=min(exp2(CS*kp),2^13)^T.
// s[n,m] = -2*sum_d Ww[d]/(1+eq*ek) (row-const dropped; softmax shift-inv;
// no max pass). Quad-rational: 4 d-terms share one rcp (rcp 1/8-rate).
// R15: (a) packed bf16 cvt (v_cvt_pk_bf16_f32) -- proj's hi/lo split was
// ~12 VALU/element x 25M stagings; now ~3. (b) score lane owns 4m (b128 ks,
// es amortized 2x) -- aggregate LDS 36 -> 23 us. Structure else = R12/R14.
// ws: eq 2MB | ekT 2MB | vph/vpl 2MB | S 4MB = 10.5MB. Ph/Pl overlay eq/ekT.

#define NROWS 1024
#define DDIM  512
#define MDIM  1024

typedef __attribute__((ext_vector_type(8))) short s8v;    // 8 bf16, 4 VGPR
typedef __attribute__((ext_vector_type(4))) float f4v;
typedef __attribute__((ext_vector_type(2))) float v2f;

__device__ __forceinline__ float bf2f(ushort h) {
    return __uint_as_float(((unsigned)h) << 16);
}
// packed RNE f32x2 -> bf16x2 (v_cvt_pk_bf16_f32 on gfx950)
__device__ __forceinline__ ushort2 f2bf2(float a, float b) {
    __hip_bfloat162 t = __float22bfloat162_rn(float2{a, b});
    union { __hip_bfloat162 v; ushort2 u; } c; c.v = t;
    return c.u;
}
// hi/lo split of 2 floats -> (h0,h1),(l0,l1)
__device__ __forceinline__ void hl2(float a, float b, ushort2& h, ushort2& l) {
    h = f2bf2(a, b);
    l = f2bf2(a - bf2f(h.x), b - bf2f(h.y));
}

__device__ __forceinline__ void load_lds16(const float* g, float* l) {
    __builtin_amdgcn_global_load_lds(
        (const __attribute__((address_space(1))) void*)g,
        (__attribute__((address_space(3))) void*)l, 16, 0, 0);
}

// ---------------- K1: fused projection GEMMs (MFMA bf16 hi/lo, A^T-B) --------
// 64x64 tile, grid (16,8,3). z=0: eq[n][d] (A=q,B=Wq, bias col, exp2; zeroes
// S). z=1: ekT[d][m] (A=Wk,B=k, bias row, exp2). z=2: vpT[d][m] (A=Wv,B=v,
// bias row, bf16 h/l out; zeroes out for ctx atomics).
__global__ __launch_bounds__(256) void proj_gemm(
    const float* __restrict__ q, const float* __restrict__ kk_,
    const float* __restrict__ v,
    const float* __restrict__ Wq, const float* __restrict__ bq,
    const float* __restrict__ Wk, const float* __restrict__ bk,
    const float* __restrict__ Wv, const float* __restrict__ bv,
    float* __restrict__ eq, float* __restrict__ ekT,
    ushort* __restrict__ vph, ushort* __restrict__ vpl,
    float* __restrict__ S, float* __restrict__ outz, float CS)
{
    __shared__ ushort Ah[4096], Al[4096], Bh[4096], Bl[4096];   // 32 KB

    const float* A; const float* B; const float* bias;
    int biasRow;
    if (blockIdx.z == 0)      { A = q;   B = Wq;  bias = bq; biasRow = 0; }
    else if (blockIdx.z == 1) { A = Wk;  B = kk_; bias = bk; biasRow = 1; }
    else                      { A = Wv;  B = v;   bias = bv; biasRow = 1; }

    const int bi = (blockIdx.z == 0) ? blockIdx.x : blockIdx.y;
    const int bj = (blockIdx.z == 0) ? blockIdx.y : blockIdx.x;

    const int t    = threadIdx.x;
    const int lane = t & 63;
    const int w    = t >> 6;
    const int lm   = lane & 15;
    const int lq   = lane >> 4;
    const int i0   = bi * 64;
    const int j0   = bj * 64;
    const int mh   = (w >> 1) * 32;
    const int nh   = (w & 1) * 32;

    // zero S (z0: 128 blocks x 32KB) and out (z2: 128 blocks x 16KB)
    if (blockIdx.z == 0) {
        const int flat = blockIdx.x * 8 + blockIdx.y;    // 0..127
        float4 zz = {0.f, 0.f, 0.f, 0.f};
#pragma unroll
        for (int p = 0; p < 8; ++p)
            *(float4*)&S[(size_t)flat * 8192 + (t + p * 256) * 4] = zz;
    } else if (blockIdx.z == 2) {
        const int flat = blockIdx.x * 8 + blockIdx.y;
        float4 zz = {0.f, 0.f, 0.f, 0.f};
#pragma unroll
        for (int p = 0; p < 4; ++p)
            *(float4*)&outz[(size_t)flat * 4096 + (t + p * 256) * 4] = zz;
    }

    f4v acc[2][2] = {{{0.f,0.f,0.f,0.f},{0.f,0.f,0.f,0.f}},
                     {{0.f,0.f,0.f,0.f},{0.f,0.f,0.f,0.f}}};
    float4 pa[4], pb[4];

    const int sr = t >> 4, sc4 = t & 15;
#pragma unroll
    for (int p = 0; p < 4; ++p) {
        int r = sr + p * 16;
        pa[p] = *(const float4*)&A[(size_t)(i0 + r) * DDIM + sc4 * 4];
        pb[p] = *(const float4*)&B[(size_t)(j0 + r) * DDIM + sc4 * 4];
    }

    for (int kc = 0; kc < 8; ++kc) {
        __syncthreads();
#pragma unroll
        for (int p = 0; p < 4; ++p) {
            int r = sr + p * 16;
            int ad = r * 64 + (((sc4 >> 1) ^ (r & 7)) << 3) + (sc4 & 1) * 4;
            ushort2 h01, l01, h23, l23;
            hl2(pa[p].x, pa[p].y, h01, l01);
            hl2(pa[p].z, pa[p].w, h23, l23);
            ushort4 ha = {h01.x, h01.y, h23.x, h23.y};
            ushort4 la = {l01.x, l01.y, l23.x, l23.y};
            *(ushort4*)&Ah[ad] = ha;
            *(ushort4*)&Al[ad] = la;
            hl2(pb[p].x, pb[p].y, h01, l01);
            hl2(pb[p].z, pb[p].w, h23, l23);
            ushort4 hb = {h01.x, h01.y, h23.x, h23.y};
            ushort4 lb = {l01.x, l01.y, l23.x, l23.y};
            *(ushort4*)&Bh[ad] = hb;
            *(ushort4*)&Bl[ad] = lb;
        }
        __syncthreads();
        if (kc < 7) {
            const int k0 = (kc + 1) * 64;
#pragma unroll
            for (int p = 0; p < 4; ++p) {
                int r = sr + p * 16;
                pa[p] = *(const float4*)&A[(size_t)(i0 + r) * DDIM + k0 + sc4 * 4];
                pb[p] = *(const float4*)&B[(size_t)(j0 + r) * DDIM + k0 + sc4 * 4];
            }
        }
#pragma unroll
        for (int ks = 0; ks < 2; ++ks) {
            const int kb = ks * 4 + lq;
            s8v afh[2], afl[2], bfh[2], bfl[2];
#pragma unroll
            for (int g = 0; g < 2; ++g) {
                int ra = mh + g * 16 + lm;
                int rb = nh + g * 16 + lm;
                int aa = ra * 64 + ((kb ^ (ra & 7)) << 3);
                int ab = rb * 64 + ((kb ^ (rb & 7)) << 3);
                afh[g] = *(const s8v*)&Ah[aa];
                afl[g] = *(const s8v*)&Al[aa];
                bfh[g] = *(const s8v*)&Bh[ab];
                bfl[g] = *(const s8v*)&Bl[ab];
            }
#pragma unroll
            for (int mi = 0; mi < 2; ++mi)
#pragma unroll
                for (int ni = 0; ni < 2; ++ni) {
                    acc[mi][ni] = __builtin_amdgcn_mfma_f32_16x16x32_bf16(
                        afh[mi], bfh[ni], acc[mi][ni], 0, 0, 0);
                    acc[mi][ni] = __builtin_amdgcn_mfma_f32_16x16x32_bf16(
                        afh[mi], bfl[ni], acc[mi][ni], 0, 0, 0);
                    acc[mi][ni] = __builtin_amdgcn_mfma_f32_16x16x32_bf16(
                        afl[mi], bfh[ni], acc[mi][ni], 0, 0, 0);
                }
        }
    }

    const float CLAMP = 8192.0f;   // 2^13: quad-rational den < 2^127
#pragma unroll
    for (int mi = 0; mi < 2; ++mi) {
#pragma unroll
        for (int ni = 0; ni < 2; ++ni) {
#pragma unroll
            for (int p = 0; p < 4; ++p) {
                int row = i0 + mh + mi * 16 + lq * 4 + p;
                int col = j0 + nh + ni * 16 + lm;
                float val = acc[mi][ni][p] + (biasRow ? bias[row] : bias[col]);
                if (blockIdx.z == 0) {
                    eq[(size_t)row * 512 + col] =
                        fminf(__builtin_amdgcn_exp2f(val * CS), CLAMP);
                } else if (blockIdx.z == 1) {
                    ekT[(size_t)row * 1024 + col] =
                        fminf(__builtin_amdgcn_exp2f(val * CS), CLAMP);
                } else {
                    ushort2 h2 = f2bf2(val, val);
                    vph[(size_t)row * 1024 + col] = h2.x;
                    ushort2 l2 = f2bf2(val - bf2f(h2.x), 0.f);
                    vpl[(size_t)row * 1024 + col] = l2.x;
                }
            }
        }
    }
}

// ---------------- K2: score v3 (4m/lane, d-split x2, atomic S) ---------------
// S[n][m] += C2 * sum_{d in half} Ww[d]/(1+eq[n][d]*ekT[d][m])
// Block: 16n x 256m x 256d; 4 waves (wave owns 4n, lane owns 4m -> 16 ILP
// chains). Grid (4 m-ch, 64 n-ch, 2 d-halves) = 512 blocks.
// ks b128 reads; es staged once per d-half; LDS aggregate ~23us (was 36).
#define DCH  32
#define SMCH 256
__global__ __launch_bounds__(256) void score_kernel(const float* __restrict__ eq,
                                                    const float* __restrict__ ekT,
                                                    const float* __restrict__ Ww,
                                                    float* __restrict__ S)
{
    __shared__ __align__(16) float ks[DCH * SMCH];   // 32 KB
    __shared__ __align__(16) float es[16 * 256];     // 16 KB
    __shared__ __align__(16) float wws[256];         // 1 KB
    const int t    = threadIdx.x;
    const int lane = t & 63;
    const int w    = t >> 6;
    const int m0   = blockIdx.x * SMCH;
    const int n0   = blockIdx.y * 16;
    const int dbase = blockIdx.z * 256;

#pragma unroll
    for (int p = 0; p < 4; ++p) {
        int idx = t + p * 256;
        int nl = idx >> 6, dd4 = idx & 63;
        *(float4*)&es[nl * 256 + dd4 * 4] =
            *(const float4*)&eq[(size_t)(n0 + nl) * DDIM + dbase + dd4 * 4];
    }
    wws[t] = Ww[dbase + t];

    v2f acc[4][2] = {};          // [nn][m-pair]
    const v2f one2 = {1.f, 1.f};

    for (int dc = 0; dc < 256; dc += DCH) {
        const int d0 = dbase + dc;
        __syncthreads();
#pragma unroll
        for (int i = 0; i < 8; ++i) {
            int r = w * 8 + i;                                   // wave-uniform
            load_lds16(ekT + (size_t)(d0 + r) * MDIM + m0 + lane * 4,
                       &ks[r * SMCH]);
        }
        __syncthreads();   // drains vmcnt -> ks visible (es/wws after 1st)

#pragma unroll
        for (int dq = 0; dq < DCH; dq += 4) {
            float4 k0 = *(const float4*)&ks[(dq + 0) * SMCH + lane * 4];
            float4 k1 = *(const float4*)&ks[(dq + 1) * SMCH + lane * 4];
            float4 k2 = *(const float4*)&ks[(dq + 2) * SMCH + lane * 4];
            float4 k3 = *(const float4*)&ks[(dq + 3) * SMCH + lane * 4];
            float4 wg = *(const float4*)&wws[dc + dq];
            v2f k0p[2] = {{k0.x, k0.y}, {k0.z, k0.w}};
            v2f k1p[2] = {{k1.x, k1.y}, {k1.z, k1.w}};
            v2f k2p[2] = {{k2.x, k2.y}, {k2.z, k2.w}};
            v2f k3p[2] = {{k3.x, k3.y}, {k3.z, k3.w}};
#pragma unroll
            for (int nn = 0; nn < 4; ++nn) {
                float4 eg = *(const float4*)&es[(w * 4 + nn) * 256 + dc + dq];
#pragma unroll
                for (int h = 0; h < 2; ++h) {
                    v2f A0 = __builtin_elementwise_fma(k0p[h], (v2f){eg.x, eg.x}, one2);
                    v2f A1 = __builtin_elementwise_fma(k1p[h], (v2f){eg.y, eg.y}, one2);
                    v2f A2 = __builtin_elementwise_fma(k2p[h], (v2f){eg.z, eg.z}, one2);
                    v2f A3 = __builtin_elementwise_fma(k3p[h], (v2f){eg.w, eg.w}, one2);
                    v2f n01 = __builtin_elementwise_fma((v2f){wg.y, wg.y}, A0,
                                                        (v2f){wg.x, wg.x} * A1);
                    v2f d01 = A0 * A1;
                    v2f n23 = __builtin_elementwise_fma((v2f){wg.w, wg.w}, A2,
                                                        (v2f){wg.z, wg.z} * A3);
                    v2f d23 = A2 * A3;
                    v2f num = __builtin_elementwise_fma(n01, d23, n23 * d01);
                    v2f den = d01 * d23;
                    v2f r = {__builtin_amdgcn_rcpf(den.x), __builtin_amdgcn_rcpf(den.y)};
                    acc[nn][h] = __builtin_elementwise_fma(num, r, acc[nn][h]);
                }
            }
        }
    }

    const float C2 = -2.8853900817779268f;   // -2*log2(e)
    const int m = m0 + lane * 4;
#pragma unroll
    for (int nn = 0; nn < 4; ++nn) {
        int n = n0 + w * 4 + nn;
        atomicAdd(&S[(size_t)n * MDIM + m + 0], acc[nn][0].x * C2);
        atomicAdd(&S[(size_t)n * MDIM + m + 1], acc[nn][0].y * C2);
        atomicAdd(&S[(size_t)n * MDIM + m + 2], acc[nn][1].x * C2);
        atomicAdd(&S[(size_t)n * MDIM + m + 3], acc[nn][1].y * C2);
    }
}

// ---------------- K2b: combine S -> P(bf16 h/l) + rowsum ---------------------
__global__ __launch_bounds__(256) void combine_kernel(const float* __restrict__ S,
                                                      const int* __restrict__ mask,
                                                      ushort* __restrict__ Ph,
                                                      ushort* __restrict__ Pl,
                                                      float* __restrict__ rsum)
{
    __shared__ float red[4];
    const int n = blockIdx.x, t = threadIdx.x;
    const int lane = t & 63, w = t >> 6;

    float4 s  = *(const float4*)&S[(size_t)n * MDIM + t * 4];
    int4   mk = *(const int4*)&mask[(size_t)n * MDIM + t * 4];
    float p0 = mk.x ? __builtin_amdgcn_exp2f(s.x) : 0.f;
    float p1 = mk.y ? __builtin_amdgcn_exp2f(s.y) : 0.f;
    float p2 = mk.z ? __builtin_amdgcn_exp2f(s.z) : 0.f;
    float p3 = mk.w ? __builtin_amdgcn_exp2f(s.w) : 0.f;

    ushort2 h01, l01, h23, l23;
    hl2(p0, p1, h01, l01);
    hl2(p2, p3, h23, l23);
    ushort4 hv = {h01.x, h01.y, h23.x, h23.y};
    ushort4 lv = {l01.x, l01.y, l23.x, l23.y};
    *(ushort4*)&Ph[(size_t)n * MDIM + t * 4] = hv;
    *(ushort4*)&Pl[(size_t)n * MDIM + t * 4] = lv;

    float rs = (p0 + p1) + (p2 + p3);
#pragma unroll
    for (int off = 32; off; off >>= 1) rs += __shfl_xor(rs, off);
    if (lane == 0) red[w] = rs;
    __syncthreads();
    if (t == 0) rsum[n] = (red[0] + red[1]) + (red[2] + red[3]);
}

// ---------------- K3: context MFMA (LDS-free, m-split x2, atomic out) --------
__global__ __launch_bounds__(256) void ctx_gemm(const ushort* __restrict__ Ph,
                                                const ushort* __restrict__ Pl,
                                                const ushort* __restrict__ vph,
                                                const ushort* __restrict__ vpl,
                                                const float* __restrict__ rsum,
                                                float* __restrict__ out)
{
    const int t    = threadIdx.x;
    const int lane = t & 63;
    const int w    = t >> 6;
    const int lm   = lane & 15;
    const int lq   = lane >> 4;
    const int d0   = blockIdx.x * 64 + w * 16;
    const int n0   = blockIdx.y * 16;
    const int mb   = blockIdx.z * 512;

    const ushort* pAh = Ph  + (size_t)(n0 + lm) * MDIM + mb + lq * 8;
    const ushort* pAl = Pl  + (size_t)(n0 + lm) * MDIM + mb + lq * 8;
    const ushort* pBh = vph + (size_t)(d0 + lm) * MDIM + mb + lq * 8;
    const ushort* pBl = vpl + (size_t)(d0 + lm) * MDIM + mb + lq * 8;

    f4v acc = {0.f, 0.f, 0.f, 0.f};
#pragma unroll 4
    for (int m0 = 0; m0 < 512; m0 += 32) {
        s8v ah = *(const s8v*)(pAh + m0);
        s8v al = *(const s8v*)(pAl + m0);
        s8v bh = *(const s8v*)(pBh + m0);
        s8v bl = *(const s8v*)(pBl + m0);
        acc = __builtin_amdgcn_mfma_f32_16x16x32_bf16(ah, bh, acc, 0, 0, 0);
        acc = __builtin_amdgcn_mfma_f32_16x16x32_bf16(ah, bl, acc, 0, 0, 0);
        acc = __builtin_amdgcn_mfma_f32_16x16x32_bf16(al, bh, acc, 0, 0, 0);
    }

#pragma unroll
    for (int p = 0; p < 4; ++p) {
        int nrow = n0 + lq * 4 + p;
        float inv = __builtin_amdgcn_rcpf(rsum[nrow]);
        atomicAdd(&out[(size_t)nrow * DDIM + d0 + lm], acc[p] * inv);
    }
}

extern "C" void kernel_launch(void* const* d_in, const int* in_sizes, int n_in,
                              void* d_out, int out_size, void* d_ws, size_t ws_size,
                              hipStream_t stream)
{
    const float* q    = (const float*)d_in[0];
    const float* k    = (const float*)d_in[1];
    const float* v    = (const float*)d_in[2];
    const int*   mask = (const int*)d_in[3];
    const float* Wq   = (const float*)d_in[4];
    const float* bq   = (const float*)d_in[5];
    const float* Wk   = (const float*)d_in[6];
    const float* bk   = (const float*)d_in[7];
    const float* Wv   = (const float*)d_in[8];
    const float* bv   = (const float*)d_in[9];
    const float* Ww   = (const float*)d_in[10];
    // d_in[11] (bw) cancels under softmax.

    float* ws    = (float*)d_ws;
    float* eq    = ws;                       // 512K floats [1024 n][512 d]
    float* ekT   = ws + 524288;              // 512K [512 d][1024 m]
    ushort* vph  = (ushort*)(ws + 1048576);  // 1M ushorts [512 d][1024 m]
    ushort* vpl  = (ushort*)(ws + 1310720);  // 1M ushorts
    float* S     = ws + 1572864;             // 1M floats [1024 n][1024 m]
    float* rsum  = ws + 2621440;             // 1K floats
    // Ph/Pl OVERLAY eq/ekT (dead after score; written by combine):
    ushort* Ph   = (ushort*)ws;              // 1M ushorts [1024 n][1024 m]
    ushort* Pl   = (ushort*)(ws + 524288);   // 1M ushorts
    float* out   = (float*)d_out;

    const float CS = 2.8853900817779268f;    // 2*log2(e)

    proj_gemm<<<dim3(16, 8, 3), dim3(256), 0, stream>>>(q, k, v, Wq, bq, Wk, bk,
                                                        Wv, bv, eq, ekT,
                                                        vph, vpl, S, out, CS);
    score_kernel<<<dim3(4, 64, 2), dim3(256), 0, stream>>>(eq, ekT, Ww, S);
    combine_kernel<<<dim3(1024), dim3(256), 0, stream>>>(S, mask, Ph, Pl, rsum);
    ctx_gemm<<<dim3(8, 64, 2), dim3(256), 0, stream>>>(Ph, Pl, vph, vpl, rsum, out);
}

// Round 17
// 184.669 us; speedup vs baseline: 1.0581x; 1.0581x over previous
//
#include <hip/hip_runtime.h>
#include <hip/hip_bf16.h>
#include <float.h>

// N=1024, M=1024, D=512, fp32 in/out.
// tanh(q+k) = 1 - 2/(1+exp2(CS*(q+k))), CS=2*log2(e), exp2 factorized:
// eq[n][d]=min(exp2(CS*qp),2^13), ekT[d][m]=min(exp2(CS*kp),2^13)^T.
// s[n,m] = -2*sum_d Ww[d]/(1+eq*ek) (row-const dropped; softmax shift-inv;
// no max pass). Quad-rational: 4 d-terms share one rcp (rcp 1/8-rate).
// R17: 3 kernels (combine + S DELETED; cooperative launch failed in R16 and
// is abandoned). Score is full-d per block (16n x 128m x 512d, 512 blocks),
// es staged ONCE (32KB), and emits P=mask?exp2(s):0 as bf16 h/l DIRECTLY
// plus shuffle-reduced rowsum atomics. Ph/Pl get fresh ws (no overlay).
// ws: eq 2MB | ekT 2MB | vph/vpl 2MB | Ph/Pl 4MB | rsum 4KB = 10.0 MB.

#define NROWS 1024
#define DDIM  512
#define MDIM  1024

typedef __attribute__((ext_vector_type(8))) short s8v;    // 8 bf16, 4 VGPR
typedef __attribute__((ext_vector_type(4))) float f4v;
typedef __attribute__((ext_vector_type(2))) float v2f;

__device__ __forceinline__ float bf2f(ushort h) {
    return __uint_as_float(((unsigned)h) << 16);
}
__device__ __forceinline__ ushort2 f2bf2(float a, float b) {   // packed cvt
    __hip_bfloat162 t = __float22bfloat162_rn(float2{a, b});
    union { __hip_bfloat162 v; ushort2 u; } c; c.v = t;
    return c.u;
}
__device__ __forceinline__ void hl2(float a, float b, ushort2& h, ushort2& l) {
    h = f2bf2(a, b);
    l = f2bf2(a - bf2f(h.x), b - bf2f(h.y));
}

__device__ __forceinline__ void load_lds16(const float* g, float* l) {
    __builtin_amdgcn_global_load_lds(
        (const __attribute__((address_space(1))) void*)g,
        (__attribute__((address_space(3))) void*)l, 16, 0, 0);
}

// ---------------- K1: fused projection GEMMs (MFMA bf16 hi/lo, A^T-B) --------
// 64x64 tile, grid (16,8,3). z=0: eq[n][d] (A=q,B=Wq, bias col, exp2; block
// (0,0,0) zeroes rsum). z=1: ekT[d][m] (A=Wk,B=k, bias row, exp2).
// z=2: vpT[d][m] (A=Wv,B=v, bias row, bf16 h/l; zeroes out for ctx atomics).
__global__ __launch_bounds__(256) void proj_gemm(
    const float* __restrict__ q, const float* __restrict__ kk_,
    const float* __restrict__ v,
    const float* __restrict__ Wq, const float* __restrict__ bq,
    const float* __restrict__ Wk, const float* __restrict__ bk,
    const float* __restrict__ Wv, const float* __restrict__ bv,
    float* __restrict__ eq, float* __restrict__ ekT,
    ushort* __restrict__ vph, ushort* __restrict__ vpl,
    float* __restrict__ rsum, float* __restrict__ outz, float CS)
{
    __shared__ ushort Ah[4096], Al[4096], Bh[4096], Bl[4096];   // 32 KB

    const float* A; const float* B; const float* bias;
    int biasRow;
    if (blockIdx.z == 0)      { A = q;   B = Wq;  bias = bq; biasRow = 0; }
    else if (blockIdx.z == 1) { A = Wk;  B = kk_; bias = bk; biasRow = 1; }
    else                      { A = Wv;  B = v;   bias = bv; biasRow = 1; }

    const int bi = (blockIdx.z == 0) ? blockIdx.x : blockIdx.y;
    const int bj = (blockIdx.z == 0) ? blockIdx.y : blockIdx.x;

    const int t    = threadIdx.x;
    const int lane = t & 63;
    const int w    = t >> 6;
    const int lm   = lane & 15;
    const int lq   = lane >> 4;
    const int i0   = bi * 64;
    const int j0   = bj * 64;
    const int mh   = (w >> 1) * 32;
    const int nh   = (w & 1) * 32;

    if (blockIdx.z == 0 && blockIdx.x == 0 && blockIdx.y == 0) {
        *(float4*)&rsum[t * 4] = float4{0.f, 0.f, 0.f, 0.f};   // 4 KB
    } else if (blockIdx.z == 2) {
        const int flat = blockIdx.x * 8 + blockIdx.y;          // 0..127
        float4 zz = {0.f, 0.f, 0.f, 0.f};
#pragma unroll
        for (int p = 0; p < 4; ++p)
            *(float4*)&outz[(size_t)flat * 4096 + (t + p * 256) * 4] = zz;
    }

    f4v acc[2][2] = {{{0.f,0.f,0.f,0.f},{0.f,0.f,0.f,0.f}},
                     {{0.f,0.f,0.f,0.f},{0.f,0.f,0.f,0.f}}};
    float4 pa[4], pb[4];

    const int sr = t >> 4, sc4 = t & 15;
#pragma unroll
    for (int p = 0; p < 4; ++p) {
        int r = sr + p * 16;
        pa[p] = *(const float4*)&A[(size_t)(i0 + r) * DDIM + sc4 * 4];
        pb[p] = *(const float4*)&B[(size_t)(j0 + r) * DDIM + sc4 * 4];
    }

    for (int kc = 0; kc < 8; ++kc) {
        __syncthreads();
#pragma unroll
        for (int p = 0; p < 4; ++p) {
            int r = sr + p * 16;
            int ad = r * 64 + (((sc4 >> 1) ^ (r & 7)) << 3) + (sc4 & 1) * 4;
            ushort2 h01, l01, h23, l23;
            hl2(pa[p].x, pa[p].y, h01, l01);
            hl2(pa[p].z, pa[p].w, h23, l23);
            ushort4 ha = {h01.x, h01.y, h23.x, h23.y};
            ushort4 la = {l01.x, l01.y, l23.x, l23.y};
            *(ushort4*)&Ah[ad] = ha;
            *(ushort4*)&Al[ad] = la;
            hl2(pb[p].x, pb[p].y, h01, l01);
            hl2(pb[p].z, pb[p].w, h23, l23);
            ushort4 hb = {h01.x, h01.y, h23.x, h23.y};
            ushort4 lb = {l01.x, l01.y, l23.x, l23.y};
            *(ushort4*)&Bh[ad] = hb;
            *(ushort4*)&Bl[ad] = lb;
        }
        __syncthreads();
        if (kc < 7) {
            const int k0 = (kc + 1) * 64;
#pragma unroll
            for (int p = 0; p < 4; ++p) {
                int r = sr + p * 16;
                pa[p] = *(const float4*)&A[(size_t)(i0 + r) * DDIM + k0 + sc4 * 4];
                pb[p] = *(const float4*)&B[(size_t)(j0 + r) * DDIM + k0 + sc4 * 4];
            }
        }
#pragma unroll
        for (int ks = 0; ks < 2; ++ks) {
            const int kb = ks * 4 + lq;
            s8v afh[2], afl[2], bfh[2], bfl[2];
#pragma unroll
            for (int g = 0; g < 2; ++g) {
                int ra = mh + g * 16 + lm;
                int rb = nh + g * 16 + lm;
                int aa = ra * 64 + ((kb ^ (ra & 7)) << 3);
                int ab = rb * 64 + ((kb ^ (rb & 7)) << 3);
                afh[g] = *(const s8v*)&Ah[aa];
                afl[g] = *(const s8v*)&Al[aa];
                bfh[g] = *(const s8v*)&Bh[ab];
                bfl[g] = *(const s8v*)&Bl[ab];
            }
#pragma unroll
            for (int mi = 0; mi < 2; ++mi)
#pragma unroll
                for (int ni = 0; ni < 2; ++ni) {
                    acc[mi][ni] = __builtin_amdgcn_mfma_f32_16x16x32_bf16(
                        afh[mi], bfh[ni], acc[mi][ni], 0, 0, 0);
                    acc[mi][ni] = __builtin_amdgcn_mfma_f32_16x16x32_bf16(
                        afh[mi], bfl[ni], acc[mi][ni], 0, 0, 0);
                    acc[mi][ni] = __builtin_amdgcn_mfma_f32_16x16x32_bf16(
                        afl[mi], bfh[ni], acc[mi][ni], 0, 0, 0);
                }
        }
    }

    const float CLAMP = 8192.0f;   // 2^13: quad-rational den < 2^127
#pragma unroll
    for (int mi = 0; mi < 2; ++mi) {
#pragma unroll
        for (int ni = 0; ni < 2; ++ni) {
#pragma unroll
            for (int p = 0; p < 4; ++p) {
                int row = i0 + mh + mi * 16 + lq * 4 + p;
                int col = j0 + nh + ni * 16 + lm;
                float val = acc[mi][ni][p] + (biasRow ? bias[row] : bias[col]);
                if (blockIdx.z == 0) {
                    eq[(size_t)row * 512 + col] =
                        fminf(__builtin_amdgcn_exp2f(val * CS), CLAMP);
                } else if (blockIdx.z == 1) {
                    ekT[(size_t)row * 1024 + col] =
                        fminf(__builtin_amdgcn_exp2f(val * CS), CLAMP);
                } else {
                    ushort2 h2 = f2bf2(val, val);
                    vph[(size_t)row * 1024 + col] = h2.x;
                    ushort2 l2 = f2bf2(val - bf2f(h2.x), 0.f);
                    vpl[(size_t)row * 1024 + col] = l2.x;
                }
            }
        }
    }
}

// ---------------- K2: score -> P(bf16 h/l) + rowsum (full d, no S) -----------
// P[n][m] = mask[n][m] ? exp(-2*sum_d Ww[d]/(1+eq[n][d]*ekT[d][m])) : 0
// Block 16n x 128m x FULL 512d; 4 waves (wave owns 4n, lane owns 2m).
// Grid (8 m-ch, 64 n-ch) = 512 blocks. es (16x512) + Ww staged ONCE (34KB
// LDS); per-chunk only ks via global_load_lds. Epilogue: coalesced int2 mask,
// coalesced ushort2 Ph/Pl stores, shuffle rowsum + 1 atomic per (row,block).
#define DCH  32
#define SMCH 128
__global__ __launch_bounds__(256) void score_kernel(const float* __restrict__ eq,
                                                    const float* __restrict__ ekT,
                                                    const float* __restrict__ Ww,
                                                    const int* __restrict__ mask,
                                                    ushort* __restrict__ Ph,
                                                    ushort* __restrict__ Pl,
                                                    float* __restrict__ rsum)
{
    __shared__ __align__(16) float ks[DCH * SMCH];   // 16 KB
    __shared__ __align__(16) float es[16 * 512];     // 32 KB (full d)
    __shared__ __align__(16) float wws[512];         // 2 KB
    const int t    = threadIdx.x;
    const int lane = t & 63;
    const int w    = t >> 6;
    const int m0   = blockIdx.x * SMCH;
    const int n0   = blockIdx.y * 16;

    // stage eq rows + Ww once (coalesced float4)
#pragma unroll
    for (int p = 0; p < 8; ++p) {
        int idx = t + p * 256;                       // 2048 float4-slots
        int nl = idx >> 7, dd4 = idx & 127;
        *(float4*)&es[nl * 512 + dd4 * 4] =
            *(const float4*)&eq[(size_t)(n0 + nl) * DDIM + dd4 * 4];
    }
    wws[t] = Ww[t];
    wws[t + 256] = Ww[t + 256];

    v2f acc[4] = {};
    const v2f one2 = {1.f, 1.f};

    for (int d0 = 0; d0 < DDIM; d0 += DCH) {
        __syncthreads();
#pragma unroll
        for (int i = 0; i < 4; ++i) {
            int r2 = w * 8 + i * 2;                              // wave-uniform
            const float* g = ekT + (size_t)(d0 + r2 + (lane >> 5)) * MDIM
                             + m0 + (lane & 31) * 4;
            load_lds16(g, &ks[r2 * SMCH]);
        }
        __syncthreads();   // drains vmcnt -> ks visible (es/wws after 1st)

#pragma unroll
        for (int dq = 0; dq < DCH; dq += 4) {
            v2f k0 = *(const v2f*)&ks[(dq + 0) * SMCH + lane * 2];
            v2f k1 = *(const v2f*)&ks[(dq + 1) * SMCH + lane * 2];
            v2f k2 = *(const v2f*)&ks[(dq + 2) * SMCH + lane * 2];
            v2f k3 = *(const v2f*)&ks[(dq + 3) * SMCH + lane * 2];
            float4 wg = *(const float4*)&wws[d0 + dq];
#pragma unroll
            for (int nn = 0; nn < 4; ++nn) {
                float4 eg = *(const float4*)&es[(w * 4 + nn) * 512 + d0 + dq];
                v2f A0 = __builtin_elementwise_fma(k0, (v2f){eg.x, eg.x}, one2);
                v2f A1 = __builtin_elementwise_fma(k1, (v2f){eg.y, eg.y}, one2);
                v2f A2 = __builtin_elementwise_fma(k2, (v2f){eg.z, eg.z}, one2);
                v2f A3 = __builtin_elementwise_fma(k3, (v2f){eg.w, eg.w}, one2);
                v2f n01 = __builtin_elementwise_fma((v2f){wg.y, wg.y}, A0,
                                                    (v2f){wg.x, wg.x} * A1);
                v2f d01 = A0 * A1;
                v2f n23 = __builtin_elementwise_fma((v2f){wg.w, wg.w}, A2,
                                                    (v2f){wg.z, wg.z} * A3);
                v2f d23 = A2 * A3;
                v2f num = __builtin_elementwise_fma(n01, d23, n23 * d01);
                v2f den = d01 * d23;
                v2f r = {__builtin_amdgcn_rcpf(den.x), __builtin_amdgcn_rcpf(den.y)};
                acc[nn] = __builtin_elementwise_fma(num, r, acc[nn]);
            }
        }
    }

    const float C2 = -2.8853900817779268f;   // -2*log2(e)
    const int m = m0 + lane * 2;
#pragma unroll
    for (int nn = 0; nn < 4; ++nn) {
        int n = n0 + w * 4 + nn;
        int2 mk = *(const int2*)&mask[(size_t)n * MDIM + m];     // coalesced
        float p0 = mk.x ? __builtin_amdgcn_exp2f(acc[nn].x * C2) : 0.f;
        float p1 = mk.y ? __builtin_amdgcn_exp2f(acc[nn].y * C2) : 0.f;
        ushort2 h, l;
        hl2(p0, p1, h, l);
        *(ushort2*)&Ph[(size_t)n * MDIM + m] = h;                // coalesced
        *(ushort2*)&Pl[(size_t)n * MDIM + m] = l;
        float rs = p0 + p1;
#pragma unroll
        for (int off = 32; off; off >>= 1) rs += __shfl_xor(rs, off);
        if (lane == 0) atomicAdd(&rsum[n], rs);
    }
}

// ---------------- K3: context MFMA (LDS-free, m-split x2, atomic out) --------
// out[n][d] += (sum_{m in half} P[n][m]*vpT[d][m]) * rcp(rsum[n])
// Wave = one 16x16 D-tile. Grid (8 d-groups, 64 n-tiles, 2 m-halves) = 1024
// blocks. out pre-zeroed by proj z2; rsum complete (K2 finished).
__global__ __launch_bounds__(256) void ctx_gemm(const ushort* __restrict__ Ph,
                                                const ushort* __restrict__ Pl,
                                                const ushort* __restrict__ vph,
                                                const ushort* __restrict__ vpl,
                                                const float* __restrict__ rsum,
                                                float* __restrict__ out)
{
    const int t    = threadIdx.x;
    const int lane = t & 63;
    const int w    = t >> 6;
    const int lm   = lane & 15;
    const int lq   = lane >> 4;
    const int d0   = blockIdx.x * 64 + w * 16;
    const int n0   = blockIdx.y * 16;
    const int mb   = blockIdx.z * 512;

    const ushort* pAh = Ph  + (size_t)(n0 + lm) * MDIM + mb + lq * 8;
    const ushort* pAl = Pl  + (size_t)(n0 + lm) * MDIM + mb + lq * 8;
    const ushort* pBh = vph + (size_t)(d0 + lm) * MDIM + mb + lq * 8;
    const ushort* pBl = vpl + (size_t)(d0 + lm) * MDIM + mb + lq * 8;

    f4v acc = {0.f, 0.f, 0.f, 0.f};
#pragma unroll 4
    for (int m0 = 0; m0 < 512; m0 += 32) {
        s8v ah = *(const s8v*)(pAh + m0);
        s8v al = *(const s8v*)(pAl + m0);
        s8v bh = *(const s8v*)(pBh + m0);
        s8v bl = *(const s8v*)(pBl + m0);
        acc = __builtin_amdgcn_mfma_f32_16x16x32_bf16(ah, bh, acc, 0, 0, 0);
        acc = __builtin_amdgcn_mfma_f32_16x16x32_bf16(ah, bl, acc, 0, 0, 0);
        acc = __builtin_amdgcn_mfma_f32_16x16x32_bf16(al, bh, acc, 0, 0, 0);
    }

#pragma unroll
    for (int p = 0; p < 4; ++p) {
        int nrow = n0 + lq * 4 + p;
        float inv = __builtin_amdgcn_rcpf(rsum[nrow]);
        atomicAdd(&out[(size_t)nrow * DDIM + d0 + lm], acc[p] * inv);
    }
}

extern "C" void kernel_launch(void* const* d_in, const int* in_sizes, int n_in,
                              void* d_out, int out_size, void* d_ws, size_t ws_size,
                              hipStream_t stream)
{
    const float* q    = (const float*)d_in[0];
    const float* k    = (const float*)d_in[1];
    const float* v    = (const float*)d_in[2];
    const int*   mask = (const int*)d_in[3];
    const float* Wq   = (const float*)d_in[4];
    const float* bq   = (const float*)d_in[5];
    const float* Wk   = (const float*)d_in[6];
    const float* bk   = (const float*)d_in[7];
    const float* Wv   = (const float*)d_in[8];
    const float* bv   = (const float*)d_in[9];
    const float* Ww   = (const float*)d_in[10];
    // d_in[11] (bw) cancels under softmax.

    float* ws    = (float*)d_ws;
    float* eq    = ws;                       // 512K floats [1024 n][512 d]
    float* ekT   = ws + 524288;              // 512K [512 d][1024 m]
    ushort* vph  = (ushort*)(ws + 1048576);  // 1M ushorts [512 d][1024 m]
    ushort* vpl  = (ushort*)(ws + 1310720);  // 1M ushorts
    ushort* Ph   = (ushort*)(ws + 1572864);  // 1M ushorts [1024 n][1024 m]
    ushort* Pl   = (ushort*)(ws + 2097152);  // 1M ushorts
    float* rsum  = ws + 2621440;             // 1K floats
    float* out   = (float*)d_out;

    const float CS = 2.8853900817779268f;    // 2*log2(e)

    proj_gemm<<<dim3(16, 8, 3), dim3(256), 0, stream>>>(q, k, v, Wq, bq, Wk, bk,
                                                        Wv, bv, eq, ekT,
                                                        vph, vpl, rsum, out, CS);
    score_kernel<<<dim3(8, 64), dim3(256), 0, stream>>>(eq, ekT, Ww, mask,
                                                        Ph, Pl, rsum);
    ctx_gemm<<<dim3(8, 64, 2), dim3(256), 0, stream>>>(Ph, Pl, vph, vpl, rsum, out);
}

// Round 18
// 178.879 us; speedup vs baseline: 1.0923x; 1.0324x over previous
//
#include <hip/hip_runtime.h>
#include <hip/hip_bf16.h>
#include <float.h>

// N=1024, M=1024, D=512, fp32 in/out.
// tanh(q+k) = 1 - 2/(1+exp2(CS*(q+k))), CS=2*log2(e), exp2 factorized:
// eq[n][d]=min(exp2(CS*qp),2^13), ekT[d][m]=min(exp2(CS*kp),2^13)^T.
// s[n,m] = -2*sum_d Ww[d]/(1+eq*ek) (row-const dropped; softmax shift-inv;
// no max pass). Quad-rational: 4 d-terms share one rcp (rcp 1/8-rate).
// R18 = R12 (best, 181.4) + score d-split x4 (2048 blocks = 8/CU; score was
// grid-limited at 4/CU) + packed v_cvt_pk_bf16_f32 conversions (R15).
// ws: eq 2MB | ekT 2MB | vph/vpl 2MB | S 4MB = 10.5MB. Ph/Pl overlay eq/ekT.

#define NROWS 1024
#define DDIM  512
#define MDIM  1024

typedef __attribute__((ext_vector_type(8))) short s8v;    // 8 bf16, 4 VGPR
typedef __attribute__((ext_vector_type(4))) float f4v;
typedef __attribute__((ext_vector_type(2))) float v2f;

__device__ __forceinline__ float bf2f(ushort h) {
    return __uint_as_float(((unsigned)h) << 16);
}
__device__ __forceinline__ ushort2 f2bf2(float a, float b) {   // packed cvt
    __hip_bfloat162 t = __float22bfloat162_rn(float2{a, b});
    union { __hip_bfloat162 v; ushort2 u; } c; c.v = t;
    return c.u;
}
__device__ __forceinline__ void hl2(float a, float b, ushort2& h, ushort2& l) {
    h = f2bf2(a, b);
    l = f2bf2(a - bf2f(h.x), b - bf2f(h.y));
}

__device__ __forceinline__ void load_lds16(const float* g, float* l) {
    __builtin_amdgcn_global_load_lds(
        (const __attribute__((address_space(1))) void*)g,
        (__attribute__((address_space(3))) void*)l, 16, 0, 0);
}

// ---------------- K1: fused projection GEMMs (MFMA bf16 hi/lo, A^T-B) --------
// z=0: eq[n][d]:  A=q,  B=Wq, bias col, exp2+clamp. Also zeroes S.
// z=1: ekT[d][m]: A=Wk, B=kk, bias row, exp2+clamp.
// z=2: vpT[d][m]: A=Wv, B=v,  bias row, bf16 h/l out.
__global__ __launch_bounds__(256) void proj_gemm(
    const float* __restrict__ q, const float* __restrict__ kk_,
    const float* __restrict__ v,
    const float* __restrict__ Wq, const float* __restrict__ bq,
    const float* __restrict__ Wk, const float* __restrict__ bk,
    const float* __restrict__ Wv, const float* __restrict__ bv,
    float* __restrict__ eq, float* __restrict__ ekT,
    ushort* __restrict__ vph, ushort* __restrict__ vpl,
    float* __restrict__ S, float CS)
{
    __shared__ ushort Ah[4096], Al[4096], Bh[4096], Bl[4096];   // 32 KB

    const float* A; const float* B; const float* bias;
    int biasRow;
    if (blockIdx.z == 0)      { A = q;   B = Wq;  bias = bq; biasRow = 0; }
    else if (blockIdx.z == 1) { A = Wk;  B = kk_; bias = bk; biasRow = 1; }
    else                      { A = Wv;  B = v;   bias = bv; biasRow = 1; }

    const int bi = (blockIdx.z == 0) ? blockIdx.x : blockIdx.y;
    const int bj = (blockIdx.z == 0) ? blockIdx.y : blockIdx.x;

    const int t    = threadIdx.x;
    const int lane = t & 63;
    const int w    = t >> 6;
    const int lm   = lane & 15;
    const int lq   = lane >> 4;
    const int i0   = bi * 64;
    const int j0   = bj * 64;
    const int mh   = (w >> 1) * 32;
    const int nh   = (w & 1) * 32;

    // z==0 has 128 blocks; each zeroes 32KB of S (4MB total) for score atomics
    if (blockIdx.z == 0) {
        const int jb = blockIdx.x * 8 + blockIdx.y;    // 0..127
        float4 zz = {0.f, 0.f, 0.f, 0.f};
#pragma unroll
        for (int p = 0; p < 8; ++p)
            *(float4*)&S[(size_t)jb * 8192 + (t + p * 256) * 4] = zz;
    }

    f4v acc[2][2] = {{{0.f,0.f,0.f,0.f},{0.f,0.f,0.f,0.f}},
                     {{0.f,0.f,0.f,0.f},{0.f,0.f,0.f,0.f}}};
    float4 pa[4], pb[4];

    const int sr = t >> 4, sc4 = t & 15;
#pragma unroll
    for (int p = 0; p < 4; ++p) {
        int r = sr + p * 16;
        pa[p] = *(const float4*)&A[(size_t)(i0 + r) * DDIM + sc4 * 4];
        pb[p] = *(const float4*)&B[(size_t)(j0 + r) * DDIM + sc4 * 4];
    }

    for (int kc = 0; kc < 8; ++kc) {
        __syncthreads();
#pragma unroll
        for (int p = 0; p < 4; ++p) {
            int r = sr + p * 16;
            int ad = r * 64 + (((sc4 >> 1) ^ (r & 7)) << 3) + (sc4 & 1) * 4;
            ushort2 h01, l01, h23, l23;
            hl2(pa[p].x, pa[p].y, h01, l01);
            hl2(pa[p].z, pa[p].w, h23, l23);
            ushort4 ha = {h01.x, h01.y, h23.x, h23.y};
            ushort4 la = {l01.x, l01.y, l23.x, l23.y};
            *(ushort4*)&Ah[ad] = ha;
            *(ushort4*)&Al[ad] = la;
            hl2(pb[p].x, pb[p].y, h01, l01);
            hl2(pb[p].z, pb[p].w, h23, l23);
            ushort4 hb = {h01.x, h01.y, h23.x, h23.y};
            ushort4 lb = {l01.x, l01.y, l23.x, l23.y};
            *(ushort4*)&Bh[ad] = hb;
            *(ushort4*)&Bl[ad] = lb;
        }
        __syncthreads();
        if (kc < 7) {
            const int k0 = (kc + 1) * 64;
#pragma unroll
            for (int p = 0; p < 4; ++p) {
                int r = sr + p * 16;
                pa[p] = *(const float4*)&A[(size_t)(i0 + r) * DDIM + k0 + sc4 * 4];
                pb[p] = *(const float4*)&B[(size_t)(j0 + r) * DDIM + k0 + sc4 * 4];
            }
        }
#pragma unroll
        for (int ks = 0; ks < 2; ++ks) {
            const int kb = ks * 4 + lq;
            s8v afh[2], afl[2], bfh[2], bfl[2];
#pragma unroll
            for (int g = 0; g < 2; ++g) {
                int ra = mh + g * 16 + lm;
                int rb = nh + g * 16 + lm;
                int aa = ra * 64 + ((kb ^ (ra & 7)) << 3);
                int ab = rb * 64 + ((kb ^ (rb & 7)) << 3);
                afh[g] = *(const s8v*)&Ah[aa];
                afl[g] = *(const s8v*)&Al[aa];
                bfh[g] = *(const s8v*)&Bh[ab];
                bfl[g] = *(const s8v*)&Bl[ab];
            }
#pragma unroll
            for (int mi = 0; mi < 2; ++mi)
#pragma unroll
                for (int ni = 0; ni < 2; ++ni) {
                    acc[mi][ni] = __builtin_amdgcn_mfma_f32_16x16x32_bf16(
                        afh[mi], bfh[ni], acc[mi][ni], 0, 0, 0);
                    acc[mi][ni] = __builtin_amdgcn_mfma_f32_16x16x32_bf16(
                        afh[mi], bfl[ni], acc[mi][ni], 0, 0, 0);
                    acc[mi][ni] = __builtin_amdgcn_mfma_f32_16x16x32_bf16(
                        afl[mi], bfh[ni], acc[mi][ni], 0, 0, 0);
                }
        }
    }

    const float CLAMP = 8192.0f;   // 2^13: quad-rational den < 2^127
#pragma unroll
    for (int mi = 0; mi < 2; ++mi) {
#pragma unroll
        for (int ni = 0; ni < 2; ++ni) {
#pragma unroll
            for (int p = 0; p < 4; ++p) {
                int row = i0 + mh + mi * 16 + lq * 4 + p;
                int col = j0 + nh + ni * 16 + lm;
                float val = acc[mi][ni][p] + (biasRow ? bias[row] : bias[col]);
                if (blockIdx.z == 0) {
                    eq[(size_t)row * 512 + col] =
                        fminf(__builtin_amdgcn_exp2f(val * CS), CLAMP);
                } else if (blockIdx.z == 1) {
                    ekT[(size_t)row * 1024 + col] =
                        fminf(__builtin_amdgcn_exp2f(val * CS), CLAMP);
                } else {
                    ushort2 h2 = f2bf2(val, val);
                    vph[(size_t)row * 1024 + col] = h2.x;
                    ushort2 l2 = f2bf2(val - bf2f(h2.x), 0.f);
                    vpl[(size_t)row * 1024 + col] = l2.x;
                }
            }
        }
    }
}

// ---------------- K2: score (d-split x4, atomic S accumulation) --------------
// S[n][m] += C2 * sum_{d in quarter} Ww[d]/(1+eq[n][d]*ekT[d][m])
// 4 waves; wave w owns 4 n; lane owns 2 m. Block 16n x 128m x 128d.
// Grid (8 m-ch, 64 n-ch, 4 d-quarters) = 2048 blocks = 8/CU (was 4/CU --
// score was grid-limited, OccupancyPercent 28%). es+Ww staged once; LDS 25KB.
#define DCH  32
#define SMCH 128
__global__ __launch_bounds__(256) void score_kernel(const float* __restrict__ eq,
                                                    const float* __restrict__ ekT,
                                                    const float* __restrict__ Ww,
                                                    float* __restrict__ S)
{
    __shared__ __align__(16) float ks[DCH * SMCH];   // 16 KB
    __shared__ __align__(16) float es[16 * 128];     // 8 KB (d-quarter)
    __shared__ __align__(16) float wws[128];         // 0.5 KB
    const int t    = threadIdx.x;
    const int lane = t & 63;
    const int w    = t >> 6;
    const int m0   = blockIdx.x * SMCH;
    const int n0   = blockIdx.y * 16;
    const int dbase = blockIdx.z * 128;

#pragma unroll
    for (int p = 0; p < 2; ++p) {
        int idx = t + p * 256;                       // 512 float4-slots
        int nl = idx >> 5, dd4 = idx & 31;
        *(float4*)&es[nl * 128 + dd4 * 4] =
            *(const float4*)&eq[(size_t)(n0 + nl) * DDIM + dbase + dd4 * 4];
    }
    if (t < 128) wws[t] = Ww[dbase + t];

    v2f acc[4] = {};
    const v2f one2 = {1.f, 1.f};

    for (int dc = 0; dc < 128; dc += DCH) {
        const int d0 = dbase + dc;
        __syncthreads();
#pragma unroll
        for (int i = 0; i < 4; ++i) {
            int r2 = w * 8 + i * 2;                              // wave-uniform
            const float* g = ekT + (size_t)(d0 + r2 + (lane >> 5)) * MDIM
                             + m0 + (lane & 31) * 4;
            load_lds16(g, &ks[r2 * SMCH]);
        }
        __syncthreads();   // drains vmcnt -> ks visible (es/wws after 1st)

#pragma unroll
        for (int dq = 0; dq < DCH; dq += 4) {
            v2f k0 = *(const v2f*)&ks[(dq + 0) * SMCH + lane * 2];
            v2f k1 = *(const v2f*)&ks[(dq + 1) * SMCH + lane * 2];
            v2f k2 = *(const v2f*)&ks[(dq + 2) * SMCH + lane * 2];
            v2f k3 = *(const v2f*)&ks[(dq + 3) * SMCH + lane * 2];
            float4 wg = *(const float4*)&wws[dc + dq];
#pragma unroll
            for (int nn = 0; nn < 4; ++nn) {
                float4 eg = *(const float4*)&es[(w * 4 + nn) * 128 + dc + dq];
                v2f A0 = __builtin_elementwise_fma(k0, (v2f){eg.x, eg.x}, one2);
                v2f A1 = __builtin_elementwise_fma(k1, (v2f){eg.y, eg.y}, one2);
                v2f A2 = __builtin_elementwise_fma(k2, (v2f){eg.z, eg.z}, one2);
                v2f A3 = __builtin_elementwise_fma(k3, (v2f){eg.w, eg.w}, one2);
                v2f n01 = __builtin_elementwise_fma((v2f){wg.y, wg.y}, A0,
                                                    (v2f){wg.x, wg.x} * A1);
                v2f d01 = A0 * A1;
                v2f n23 = __builtin_elementwise_fma((v2f){wg.w, wg.w}, A2,
                                                    (v2f){wg.z, wg.z} * A3);
                v2f d23 = A2 * A3;
                v2f num = __builtin_elementwise_fma(n01, d23, n23 * d01);
                v2f den = d01 * d23;
                v2f r = {__builtin_amdgcn_rcpf(den.x), __builtin_amdgcn_rcpf(den.y)};
                acc[nn] = __builtin_elementwise_fma(num, r, acc[nn]);
            }
        }
    }

    const float C2 = -2.8853900817779268f;   // -2*log2(e)
    const int m = m0 + lane * 2;
#pragma unroll
    for (int nn = 0; nn < 4; ++nn) {
        int n = n0 + w * 4 + nn;
        atomicAdd(&S[(size_t)n * MDIM + m],     acc[nn].x * C2);
        atomicAdd(&S[(size_t)n * MDIM + m + 1], acc[nn].y * C2);
    }
}

// ---------------- K2b: combine S -> P(bf16 h/l) + rowsum ---------------------
__global__ __launch_bounds__(256) void combine_kernel(const float* __restrict__ S,
                                                      const int* __restrict__ mask,
                                                      ushort* __restrict__ Ph,
                                                      ushort* __restrict__ Pl,
                                                      float* __restrict__ rsum)
{
    __shared__ float red[4];
    const int n = blockIdx.x, t = threadIdx.x;
    const int lane = t & 63, w = t >> 6;

    float4 s  = *(const float4*)&S[(size_t)n * MDIM + t * 4];
    int4   mk = *(const int4*)&mask[(size_t)n * MDIM + t * 4];
    float p0 = mk.x ? __builtin_amdgcn_exp2f(s.x) : 0.f;
    float p1 = mk.y ? __builtin_amdgcn_exp2f(s.y) : 0.f;
    float p2 = mk.z ? __builtin_amdgcn_exp2f(s.z) : 0.f;
    float p3 = mk.w ? __builtin_amdgcn_exp2f(s.w) : 0.f;

    ushort2 h01, l01, h23, l23;
    hl2(p0, p1, h01, l01);
    hl2(p2, p3, h23, l23);
    ushort4 hv = {h01.x, h01.y, h23.x, h23.y};
    ushort4 lv = {l01.x, l01.y, l23.x, l23.y};
    *(ushort4*)&Ph[(size_t)n * MDIM + t * 4] = hv;
    *(ushort4*)&Pl[(size_t)n * MDIM + t * 4] = lv;

    float rs = (p0 + p1) + (p2 + p3);
#pragma unroll
    for (int off = 32; off; off >>= 1) rs += __shfl_xor(rs, off);
    if (lane == 0) red[w] = rs;
    __syncthreads();
    if (t == 0) rsum[n] = (red[0] + red[1]) + (red[2] + red[3]);
}

// ---------------- K3: context MFMA (LDS-free) --------------------------------
// out[n][d] = (sum_m P[n][m]*vpT[d][m]) * rcp(rsum[n])
__global__ __launch_bounds__(256) void ctx_gemm(const ushort* __restrict__ Ph,
                                                const ushort* __restrict__ Pl,
                                                const ushort* __restrict__ vph,
                                                const ushort* __restrict__ vpl,
                                                const float* __restrict__ rsum,
                                                float* __restrict__ out)
{
    const int t    = threadIdx.x;
    const int lane = t & 63;
    const int w    = t >> 6;
    const int lm   = lane & 15;
    const int lq   = lane >> 4;
    const int d0   = blockIdx.x * 64 + w * 16;
    const int n0   = blockIdx.y * 16;

    const ushort* pAh = Ph  + (size_t)(n0 + lm) * MDIM + lq * 8;
    const ushort* pAl = Pl  + (size_t)(n0 + lm) * MDIM + lq * 8;
    const ushort* pBh = vph + (size_t)(d0 + lm) * MDIM + lq * 8;
    const ushort* pBl = vpl + (size_t)(d0 + lm) * MDIM + lq * 8;

    f4v acc = {0.f, 0.f, 0.f, 0.f};
#pragma unroll 4
    for (int m0 = 0; m0 < MDIM; m0 += 32) {
        s8v ah = *(const s8v*)(pAh + m0);
        s8v al = *(const s8v*)(pAl + m0);
        s8v bh = *(const s8v*)(pBh + m0);
        s8v bl = *(const s8v*)(pBl + m0);
        acc = __builtin_amdgcn_mfma_f32_16x16x32_bf16(ah, bh, acc, 0, 0, 0);
        acc = __builtin_amdgcn_mfma_f32_16x16x32_bf16(ah, bl, acc, 0, 0, 0);
        acc = __builtin_amdgcn_mfma_f32_16x16x32_bf16(al, bh, acc, 0, 0, 0);
    }

#pragma unroll
    for (int p = 0; p < 4; ++p) {
        int nrow = n0 + lq * 4 + p;
        float inv = __builtin_amdgcn_rcpf(rsum[nrow]);
        out[(size_t)nrow * DDIM + d0 + lm] = acc[p] * inv;
    }
}

extern "C" void kernel_launch(void* const* d_in, const int* in_sizes, int n_in,
                              void* d_out, int out_size, void* d_ws, size_t ws_size,
                              hipStream_t stream)
{
    const float* q    = (const float*)d_in[0];
    const float* k    = (const float*)d_in[1];
    const float* v    = (const float*)d_in[2];
    const int*   mask = (const int*)d_in[3];
    const float* Wq   = (const float*)d_in[4];
    const float* bq   = (const float*)d_in[5];
    const float* Wk   = (const float*)d_in[6];
    const float* bk   = (const float*)d_in[7];
    const float* Wv   = (const float*)d_in[8];
    const float* bv   = (const float*)d_in[9];
    const float* Ww   = (const float*)d_in[10];
    // d_in[11] (bw) cancels under softmax.

    float* ws    = (float*)d_ws;
    float* eq    = ws;                       // 512K floats [1024 n][512 d]
    float* ekT   = ws + 524288;              // 512K [512 d][1024 m]
    ushort* vph  = (ushort*)(ws + 1048576);  // 1M ushorts [512 d][1024 m]
    ushort* vpl  = (ushort*)(ws + 1310720);  // 1M ushorts
    float* S     = ws + 1572864;             // 1M floats [1024 n][1024 m]
    float* rsum  = ws + 2621440;             // 1K floats
    // Ph/Pl OVERLAY eq/ekT (dead after score; written by combine):
    ushort* Ph   = (ushort*)ws;              // 1M ushorts [1024 n][1024 m]
    ushort* Pl   = (ushort*)(ws + 524288);   // 1M ushorts
    float* out   = (float*)d_out;

    const float CS = 2.8853900817779268f;    // 2*log2(e)

    proj_gemm<<<dim3(16, 8, 3), dim3(256), 0, stream>>>(q, k, v, Wq, bq, Wk, bk,
                                                        Wv, bv, eq, ekT,
                                                        vph, vpl, S, CS);
    score_kernel<<<dim3(8, 64, 4), dim3(256), 0, stream>>>(eq, ekT, Ww, S);
    combine_kernel<<<dim3(1024), dim3(256), 0, stream>>>(S, mask, Ph, Pl, rsum);
    ctx_gemm<<<dim3(8, 64), dim3(256), 0, stream>>>(Ph, Pl, vph, vpl, rsum, out);
}

// Round 19
// 177.240 us; speedup vs baseline: 1.1024x; 1.0092x over previous
//
#include <hip/hip_runtime.h>
#include <hip/hip_bf16.h>
#include <float.h>

// N=1024, M=1024, D=512, fp32 in/out.
// tanh(q+k) = 1 - 2/(1+exp2(CS*(q+k))), CS=2*log2(e), exp2 factorized:
// eq[n][d]=min(exp2(CS*qp),2^13), ekT[d][m]=min(exp2(CS*kp),2^13)^T.
// s[n,m] = -2*sum_d Ww[d]/(1+eq*ek) (row-const dropped; softmax shift-inv;
// no max pass).
// R19 = R18 + 8-term rational merge in score: ONE rcp per 8 d-terms via a
// 3-level product tree, overflow prevented by folding c=2^-13 into the
// staged eq (A' = c*A in [2^-13,2^13], den8 <= 2^104) and into Ww (num
// scales c^8 = den scale -> ratio exact). 30 pk-ops + 2 rcp per 16 elems
// (was 28 pk + 4 rcp): 7.5 -> 5.75 cyc/elem.
// ws: eq 2MB | ekT 2MB | vph/vpl 2MB | S 4MB = 10.5MB. Ph/Pl overlay eq/ekT.

#define NROWS 1024
#define DDIM  512
#define MDIM  1024

typedef __attribute__((ext_vector_type(8))) short s8v;    // 8 bf16, 4 VGPR
typedef __attribute__((ext_vector_type(4))) float f4v;
typedef __attribute__((ext_vector_type(2))) float v2f;

__device__ __forceinline__ float bf2f(ushort h) {
    return __uint_as_float(((unsigned)h) << 16);
}
__device__ __forceinline__ ushort2 f2bf2(float a, float b) {   // packed cvt
    __hip_bfloat162 t = __float22bfloat162_rn(float2{a, b});
    union { __hip_bfloat162 v; ushort2 u; } c; c.v = t;
    return c.u;
}
__device__ __forceinline__ void hl2(float a, float b, ushort2& h, ushort2& l) {
    h = f2bf2(a, b);
    l = f2bf2(a - bf2f(h.x), b - bf2f(h.y));
}

__device__ __forceinline__ void load_lds16(const float* g, float* l) {
    __builtin_amdgcn_global_load_lds(
        (const __attribute__((address_space(1))) void*)g,
        (__attribute__((address_space(3))) void*)l, 16, 0, 0);
}

// ---------------- K1: fused projection GEMMs (MFMA bf16 hi/lo, A^T-B) --------
// z=0: eq[n][d]:  A=q,  B=Wq, bias col, exp2+clamp. Also zeroes S.
// z=1: ekT[d][m]: A=Wk, B=kk, bias row, exp2+clamp.
// z=2: vpT[d][m]: A=Wv, B=v,  bias row, bf16 h/l out.
__global__ __launch_bounds__(256) void proj_gemm(
    const float* __restrict__ q, const float* __restrict__ kk_,
    const float* __restrict__ v,
    const float* __restrict__ Wq, const float* __restrict__ bq,
    const float* __restrict__ Wk, const float* __restrict__ bk,
    const float* __restrict__ Wv, const float* __restrict__ bv,
    float* __restrict__ eq, float* __restrict__ ekT,
    ushort* __restrict__ vph, ushort* __restrict__ vpl,
    float* __restrict__ S, float CS)
{
    __shared__ ushort Ah[4096], Al[4096], Bh[4096], Bl[4096];   // 32 KB

    const float* A; const float* B; const float* bias;
    int biasRow;
    if (blockIdx.z == 0)      { A = q;   B = Wq;  bias = bq; biasRow = 0; }
    else if (blockIdx.z == 1) { A = Wk;  B = kk_; bias = bk; biasRow = 1; }
    else                      { A = Wv;  B = v;   bias = bv; biasRow = 1; }

    const int bi = (blockIdx.z == 0) ? blockIdx.x : blockIdx.y;
    const int bj = (blockIdx.z == 0) ? blockIdx.y : blockIdx.x;

    const int t    = threadIdx.x;
    const int lane = t & 63;
    const int w    = t >> 6;
    const int lm   = lane & 15;
    const int lq   = lane >> 4;
    const int i0   = bi * 64;
    const int j0   = bj * 64;
    const int mh   = (w >> 1) * 32;
    const int nh   = (w & 1) * 32;

    // z==0 has 128 blocks; each zeroes 32KB of S (4MB total) for score atomics
    if (blockIdx.z == 0) {
        const int jb = blockIdx.x * 8 + blockIdx.y;    // 0..127
        float4 zz = {0.f, 0.f, 0.f, 0.f};
#pragma unroll
        for (int p = 0; p < 8; ++p)
            *(float4*)&S[(size_t)jb * 8192 + (t + p * 256) * 4] = zz;
    }

    f4v acc[2][2] = {{{0.f,0.f,0.f,0.f},{0.f,0.f,0.f,0.f}},
                     {{0.f,0.f,0.f,0.f},{0.f,0.f,0.f,0.f}}};
    float4 pa[4], pb[4];

    const int sr = t >> 4, sc4 = t & 15;
#pragma unroll
    for (int p = 0; p < 4; ++p) {
        int r = sr + p * 16;
        pa[p] = *(const float4*)&A[(size_t)(i0 + r) * DDIM + sc4 * 4];
        pb[p] = *(const float4*)&B[(size_t)(j0 + r) * DDIM + sc4 * 4];
    }

    for (int kc = 0; kc < 8; ++kc) {
        __syncthreads();
#pragma unroll
        for (int p = 0; p < 4; ++p) {
            int r = sr + p * 16;
            int ad = r * 64 + (((sc4 >> 1) ^ (r & 7)) << 3) + (sc4 & 1) * 4;
            ushort2 h01, l01, h23, l23;
            hl2(pa[p].x, pa[p].y, h01, l01);
            hl2(pa[p].z, pa[p].w, h23, l23);
            ushort4 ha = {h01.x, h01.y, h23.x, h23.y};
            ushort4 la = {l01.x, l01.y, l23.x, l23.y};
            *(ushort4*)&Ah[ad] = ha;
            *(ushort4*)&Al[ad] = la;
            hl2(pb[p].x, pb[p].y, h01, l01);
            hl2(pb[p].z, pb[p].w, h23, l23);
            ushort4 hb = {h01.x, h01.y, h23.x, h23.y};
            ushort4 lb = {l01.x, l01.y, l23.x, l23.y};
            *(ushort4*)&Bh[ad] = hb;
            *(ushort4*)&Bl[ad] = lb;
        }
        __syncthreads();
        if (kc < 7) {
            const int k0 = (kc + 1) * 64;
#pragma unroll
            for (int p = 0; p < 4; ++p) {
                int r = sr + p * 16;
                pa[p] = *(const float4*)&A[(size_t)(i0 + r) * DDIM + k0 + sc4 * 4];
                pb[p] = *(const float4*)&B[(size_t)(j0 + r) * DDIM + k0 + sc4 * 4];
            }
        }
#pragma unroll
        for (int ks = 0; ks < 2; ++ks) {
            const int kb = ks * 4 + lq;
            s8v afh[2], afl[2], bfh[2], bfl[2];
#pragma unroll
            for (int g = 0; g < 2; ++g) {
                int ra = mh + g * 16 + lm;
                int rb = nh + g * 16 + lm;
                int aa = ra * 64 + ((kb ^ (ra & 7)) << 3);
                int ab = rb * 64 + ((kb ^ (rb & 7)) << 3);
                afh[g] = *(const s8v*)&Ah[aa];
                afl[g] = *(const s8v*)&Al[aa];
                bfh[g] = *(const s8v*)&Bh[ab];
                bfl[g] = *(const s8v*)&Bl[ab];
            }
#pragma unroll
            for (int mi = 0; mi < 2; ++mi)
#pragma unroll
                for (int ni = 0; ni < 2; ++ni) {
                    acc[mi][ni] = __builtin_amdgcn_mfma_f32_16x16x32_bf16(
                        afh[mi], bfh[ni], acc[mi][ni], 0, 0, 0);
                    acc[mi][ni] = __builtin_amdgcn_mfma_f32_16x16x32_bf16(
                        afh[mi], bfl[ni], acc[mi][ni], 0, 0, 0);
                    acc[mi][ni] = __builtin_amdgcn_mfma_f32_16x16x32_bf16(
                        afl[mi], bfh[ni], acc[mi][ni], 0, 0, 0);
                }
        }
    }

    const float CLAMP = 8192.0f;   // 2^13: scaled 8-term den < 2^104
#pragma unroll
    for (int mi = 0; mi < 2; ++mi) {
#pragma unroll
        for (int ni = 0; ni < 2; ++ni) {
#pragma unroll
            for (int p = 0; p < 4; ++p) {
                int row = i0 + mh + mi * 16 + lq * 4 + p;
                int col = j0 + nh + ni * 16 + lm;
                float val = acc[mi][ni][p] + (biasRow ? bias[row] : bias[col]);
                if (blockIdx.z == 0) {
                    eq[(size_t)row * 512 + col] =
                        fminf(__builtin_amdgcn_exp2f(val * CS), CLAMP);
                } else if (blockIdx.z == 1) {
                    ekT[(size_t)row * 1024 + col] =
                        fminf(__builtin_amdgcn_exp2f(val * CS), CLAMP);
                } else {
                    ushort2 h2 = f2bf2(val, val);
                    vph[(size_t)row * 1024 + col] = h2.x;
                    ushort2 l2 = f2bf2(val - bf2f(h2.x), 0.f);
                    vpl[(size_t)row * 1024 + col] = l2.x;
                }
            }
        }
    }
}

// ---------------- K2: score (8-term merge, d-split x4, atomic S) -------------
// S[n][m] += C2 * sum_{d in quarter} Ww[d]/(1+eq[n][d]*ekT[d][m])
// 4 waves; wave w owns 4 n; lane owns 2 m. Block 16n x 128m x 128d.
// Grid (8,64,4) = 2048 blocks = 8/CU. es staged pre-scaled by c=2^-13,
// wws pre-scaled by c: A' = fma(ek, c*eq, c); num(c*w) / den(c*A) = exact.
// Tree: 4 pair-merges -> 2 -> 1 -> rcp. 30 pk + 2 rcp per (8d x 2m).
#define DCH  32
#define SMCH 128
__global__ __launch_bounds__(256) void score_kernel(const float* __restrict__ eq,
                                                    const float* __restrict__ ekT,
                                                    const float* __restrict__ Ww,
                                                    float* __restrict__ S)
{
    __shared__ __align__(16) float ks[DCH * SMCH];   // 16 KB
    __shared__ __align__(16) float es[16 * 128];     // 8 KB (d-quarter, scaled)
    __shared__ __align__(16) float wws[128];         // 0.5 KB (scaled)
    const int t    = threadIdx.x;
    const int lane = t & 63;
    const int w    = t >> 6;
    const int m0   = blockIdx.x * SMCH;
    const int n0   = blockIdx.y * 16;
    const int dbase = blockIdx.z * 128;

    const float SC = 1.220703125e-4f;        // c = 2^-13

#pragma unroll
    for (int p = 0; p < 2; ++p) {
        int idx = t + p * 256;                       // 512 float4-slots
        int nl = idx >> 5, dd4 = idx & 31;
        float4 e4 = *(const float4*)&eq[(size_t)(n0 + nl) * DDIM + dbase + dd4 * 4];
        float4 e4s = {e4.x * SC, e4.y * SC, e4.z * SC, e4.w * SC};
        *(float4*)&es[nl * 128 + dd4 * 4] = e4s;
    }
    if (t < 128) wws[t] = Ww[dbase + t] * SC;

    v2f acc[4] = {};
    const v2f cc2 = {1.220703125e-4f, 1.220703125e-4f};   // {c, c}

    for (int dc = 0; dc < 128; dc += DCH) {
        const int d0 = dbase + dc;
        __syncthreads();
#pragma unroll
        for (int i = 0; i < 4; ++i) {
            int r2 = w * 8 + i * 2;                              // wave-uniform
            const float* g = ekT + (size_t)(d0 + r2 + (lane >> 5)) * MDIM
                             + m0 + (lane & 31) * 4;
            load_lds16(g, &ks[r2 * SMCH]);
        }
        __syncthreads();   // drains vmcnt -> ks visible (es/wws after 1st)

#pragma unroll
        for (int dq = 0; dq < DCH; dq += 8) {
            v2f k0 = *(const v2f*)&ks[(dq + 0) * SMCH + lane * 2];
            v2f k1 = *(const v2f*)&ks[(dq + 1) * SMCH + lane * 2];
            v2f k2 = *(const v2f*)&ks[(dq + 2) * SMCH + lane * 2];
            v2f k3 = *(const v2f*)&ks[(dq + 3) * SMCH + lane * 2];
            v2f k4 = *(const v2f*)&ks[(dq + 4) * SMCH + lane * 2];
            v2f k5 = *(const v2f*)&ks[(dq + 5) * SMCH + lane * 2];
            v2f k6 = *(const v2f*)&ks[(dq + 6) * SMCH + lane * 2];
            v2f k7 = *(const v2f*)&ks[(dq + 7) * SMCH + lane * 2];
            float4 wgA = *(const float4*)&wws[dc + dq];
            float4 wgB = *(const float4*)&wws[dc + dq + 4];
#pragma unroll
            for (int nn = 0; nn < 4; ++nn) {
                float4 egA = *(const float4*)&es[(w * 4 + nn) * 128 + dc + dq];
                float4 egB = *(const float4*)&es[(w * 4 + nn) * 128 + dc + dq + 4];
                v2f A0 = __builtin_elementwise_fma(k0, (v2f){egA.x, egA.x}, cc2);
                v2f A1 = __builtin_elementwise_fma(k1, (v2f){egA.y, egA.y}, cc2);
                v2f A2 = __builtin_elementwise_fma(k2, (v2f){egA.z, egA.z}, cc2);
                v2f A3 = __builtin_elementwise_fma(k3, (v2f){egA.w, egA.w}, cc2);
                v2f A4 = __builtin_elementwise_fma(k4, (v2f){egB.x, egB.x}, cc2);
                v2f A5 = __builtin_elementwise_fma(k5, (v2f){egB.y, egB.y}, cc2);
                v2f A6 = __builtin_elementwise_fma(k6, (v2f){egB.z, egB.z}, cc2);
                v2f A7 = __builtin_elementwise_fma(k7, (v2f){egB.w, egB.w}, cc2);
                // level 1: pairs
                v2f n01 = __builtin_elementwise_fma((v2f){wgA.y, wgA.y}, A0,
                                                    (v2f){wgA.x, wgA.x} * A1);
                v2f d01 = A0 * A1;
                v2f n23 = __builtin_elementwise_fma((v2f){wgA.w, wgA.w}, A2,
                                                    (v2f){wgA.z, wgA.z} * A3);
                v2f d23 = A2 * A3;
                v2f n45 = __builtin_elementwise_fma((v2f){wgB.y, wgB.y}, A4,
                                                    (v2f){wgB.x, wgB.x} * A5);
                v2f d45 = A4 * A5;
                v2f n67 = __builtin_elementwise_fma((v2f){wgB.w, wgB.w}, A6,
                                                    (v2f){wgB.z, wgB.z} * A7);
                v2f d67 = A6 * A7;
                // level 2
                v2f nA = __builtin_elementwise_fma(n01, d23, n23 * d01);
                v2f dA = d01 * d23;
                v2f nB = __builtin_elementwise_fma(n45, d67, n67 * d45);
                v2f dB = d45 * d67;
                // level 3
                v2f num = __builtin_elementwise_fma(nA, dB, nB * dA);
                v2f den = dA * dB;
                v2f r = {__builtin_amdgcn_rcpf(den.x), __builtin_amdgcn_rcpf(den.y)};
                acc[nn] = __builtin_elementwise_fma(num, r, acc[nn]);
            }
        }
    }

    const float C2 = -2.8853900817779268f;   // -2*log2(e)
    const int m = m0 + lane * 2;
#pragma unroll
    for (int nn = 0; nn < 4; ++nn) {
        int n = n0 + w * 4 + nn;
        atomicAdd(&S[(size_t)n * MDIM + m],     acc[nn].x * C2);
        atomicAdd(&S[(size_t)n * MDIM + m + 1], acc[nn].y * C2);
    }
}

// ---------------- K2b: combine S -> P(bf16 h/l) + rowsum ---------------------
__global__ __launch_bounds__(256) void combine_kernel(const float* __restrict__ S,
                                                      const int* __restrict__ mask,
                                                      ushort* __restrict__ Ph,
                                                      ushort* __restrict__ Pl,
                                                      float* __restrict__ rsum)
{
    __shared__ float red[4];
    const int n = blockIdx.x, t = threadIdx.x;
    const int lane = t & 63, w = t >> 6;

    float4 s  = *(const float4*)&S[(size_t)n * MDIM + t * 4];
    int4   mk = *(const int4*)&mask[(size_t)n * MDIM + t * 4];
    float p0 = mk.x ? __builtin_amdgcn_exp2f(s.x) : 0.f;
    float p1 = mk.y ? __builtin_amdgcn_exp2f(s.y) : 0.f;
    float p2 = mk.z ? __builtin_amdgcn_exp2f(s.z) : 0.f;
    float p3 = mk.w ? __builtin_amdgcn_exp2f(s.w) : 0.f;

    ushort2 h01, l01, h23, l23;
    hl2(p0, p1, h01, l01);
    hl2(p2, p3, h23, l23);
    ushort4 hv = {h01.x, h01.y, h23.x, h23.y};
    ushort4 lv = {l01.x, l01.y, l23.x, l23.y};
    *(ushort4*)&Ph[(size_t)n * MDIM + t * 4] = hv;
    *(ushort4*)&Pl[(size_t)n * MDIM + t * 4] = lv;

    float rs = (p0 + p1) + (p2 + p3);
#pragma unroll
    for (int off = 32; off; off >>= 1) rs += __shfl_xor(rs, off);
    if (lane == 0) red[w] = rs;
    __syncthreads();
    if (t == 0) rsum[n] = (red[0] + red[1]) + (red[2] + red[3]);
}

// ---------------- K3: context MFMA (LDS-free) --------------------------------
// out[n][d] = (sum_m P[n][m]*vpT[d][m]) * rcp(rsum[n])
__global__ __launch_bounds__(256) void ctx_gemm(const ushort* __restrict__ Ph,
                                                const ushort* __restrict__ Pl,
                                                const ushort* __restrict__ vph,
                                                const ushort* __restrict__ vpl,
                                                const float* __restrict__ rsum,
                                                float* __restrict__ out)
{
    const int t    = threadIdx.x;
    const int lane = t & 63;
    const int w    = t >> 6;
    const int lm   = lane & 15;
    const int lq   = lane >> 4;
    const int d0   = blockIdx.x * 64 + w * 16;
    const int n0   = blockIdx.y * 16;

    const ushort* pAh = Ph  + (size_t)(n0 + lm) * MDIM + lq * 8;
    const ushort* pAl = Pl  + (size_t)(n0 + lm) * MDIM + lq * 8;
    const ushort* pBh = vph + (size_t)(d0 + lm) * MDIM + lq * 8;
    const ushort* pBl = vpl + (size_t)(d0 + lm) * MDIM + lq * 8;

    f4v acc = {0.f, 0.f, 0.f, 0.f};
#pragma unroll 4
    for (int m0 = 0; m0 < MDIM; m0 += 32) {
        s8v ah = *(const s8v*)(pAh + m0);
        s8v al = *(const s8v*)(pAl + m0);
        s8v bh = *(const s8v*)(pBh + m0);
        s8v bl = *(const s8v*)(pBl + m0);
        acc = __builtin_amdgcn_mfma_f32_16x16x32_bf16(ah, bh, acc, 0, 0, 0);
        acc = __builtin_amdgcn_mfma_f32_16x16x32_bf16(ah, bl, acc, 0, 0, 0);
        acc = __builtin_amdgcn_mfma_f32_16x16x32_bf16(al, bh, acc, 0, 0, 0);
    }

#pragma unroll
    for (int p = 0; p < 4; ++p) {
        int nrow = n0 + lq * 4 + p;
        float inv = __builtin_amdgcn_rcpf(rsum[nrow]);
        out[(size_t)nrow * DDIM + d0 + lm] = acc[p] * inv;
    }
}

extern "C" void kernel_launch(void* const* d_in, const int* in_sizes, int n_in,
                              void* d_out, int out_size, void* d_ws, size_t ws_size,
                              hipStream_t stream)
{
    const float* q    = (const float*)d_in[0];
    const float* k    = (const float*)d_in[1];
    const float* v    = (const float*)d_in[2];
    const int*   mask = (const int*)d_in[3];
    const float* Wq   = (const float*)d_in[4];
    const float* bq   = (const float*)d_in[5];
    const float* Wk   = (const float*)d_in[6];
    const float* bk   = (const float*)d_in[7];
    const float* Wv   = (const float*)d_in[8];
    const float* bv   = (const float*)d_in[9];
    const float* Ww   = (const float*)d_in[10];
    // d_in[11] (bw) cancels under softmax.

    float* ws    = (float*)d_ws;
    float* eq    = ws;                       // 512K floats [1024 n][512 d]
    float* ekT   = ws + 524288;              // 512K [512 d][1024 m]
    ushort* vph  = (ushort*)(ws + 1048576);  // 1M ushorts [512 d][1024 m]
    ushort* vpl  = (ushort*)(ws + 1310720);  // 1M ushorts
    float* S     = ws + 1572864;             // 1M floats [1024 n][1024 m]
    float* rsum  = ws + 2621440;             // 1K floats
    // Ph/Pl OVERLAY eq/ekT (dead after score; written by combine):
    ushort* Ph   = (ushort*)ws;              // 1M ushorts [1024 n][1024 m]
    ushort* Pl   = (ushort*)(ws + 524288);   // 1M ushorts
    float* out   = (float*)d_out;

    const float CS = 2.8853900817779268f;    // 2*log2(e)

    proj_gemm<<<dim3(16, 8, 3), dim3(256), 0, stream>>>(q, k, v, Wq, bq, Wk, bk,
                                                        Wv, bv, eq, ekT,
                                                        vph, vpl, S, CS);
    score_kernel<<<dim3(8, 64, 4), dim3(256), 0, stream>>>(eq, ekT, Ww, S);
    combine_kernel<<<dim3(1024), dim3(256), 0, stream>>>(S, mask, Ph, Pl, rsum);
    ctx_gemm<<<dim3(8, 64), dim3(256), 0, stream>>>(Ph, Pl, vph, vpl, rsum, out);
}